// Round 13
// baseline (44.718 us; speedup 1.0000x reference)
//
#include <hip/hip_runtime.h>

#define NBINS 10

constexpr int BLOCK  = 256;
constexpr int GRID   = 768;            // 3 blocks/CU (2x20KB LDS each)
constexpr int PSTR   = 32;             // padded partial-row stride (floats)
constexpr int TPAIRS = 256;            // pairs per tile (1 per thread)
constexpr int TF4    = TPAIRS * 5;     // 1280 float4 per tile
constexpr int HWORDS = TF4 * 4;        // 5120 words per LDS half

// d_ws float layout: 3 segments of GRID*PSTR floats (conf | cnt | cor).
// Every slot read by ece_reduce is rewritten every call — no memset needed.

__global__ __launch_bounds__(BLOCK) void ece_pass(
    const float4* __restrict__ p4,
    const int2*   __restrict__ l2,
    float*        __restrict__ part,
    int npairs, int nf4, int ntiles)
{
    __shared__ float4 s_buf4[2 * TF4];          // 40 KB double-buffered tile
    __shared__ float        s_red[8 * NBINS];
    __shared__ unsigned int s_cor[NBINS];
    float* s_lds = reinterpret_cast<float*>(s_buf4);

    const int tid  = threadIdx.x;
    const int lane = tid & 63, wave = tid >> 6;

    const float EDGE[NBINS] = {
        (float)(0*0.1), (float)(1*0.1), (float)(2*0.1), (float)(3*0.1), (float)(4*0.1),
        (float)(5*0.1), (float)(6*0.1), (float)(7*0.1), (float)(8*0.1), (float)(9*0.1)};

    if (tid < NBINS) s_cor[tid] = 0u;

    // LINEAR tile layout (swizzle removed — R12's XOR was non-bijective):
    // within-tile float4 j=k*256+tid holds (pair p=j/5, comp c=j%5) at word
    // addr p*20 + c*4. Read side (pair tid, comps 0..4) is an 8-way bank
    // conflict, but R4/R6 measured it at only ~32K conflict cycles — cheap.
    int waddr[5];
#pragma unroll
    for (int k = 0; k < 5; ++k) {
        const int j = k * BLOCK + tid;
        const int p = j / 5, c = j - 5 * p;
        waddr[k] = p * 20 + c * 4;
    }

    float        conf[NBINS];
    unsigned int cnt1[NBINS];           // edges 1..9 ([0] unused)
    unsigned int np = 0;                // valid pairs -> cnt[0] = 20*np (x>0 always)
#pragma unroll
    for (int t = 0; t < NBINS; ++t) { conf[t] = 0.0f; cnt1[t] = 0u; }

#define LADDER_LOW(x)                                                       \
        {                                                                   \
            _Pragma("unroll")                                               \
            for (int t_ = 1; t_ <= 4; ++t_) {                               \
                const bool g_ = (x) > EDGE[t_];                             \
                cnt1[t_] += g_ ? 1u : 0u;                                   \
                conf[t_] += g_ ? (x) : 0.0f;                                \
            }                                                               \
        }
#define LADDER_HIGH(x)                                                      \
        {                                                                   \
            _Pragma("unroll")                                               \
            for (int t_ = 5; t_ < NBINS; ++t_) {                            \
                const bool g_ = (x) > EDGE[t_];                             \
                cnt1[t_] += g_ ? 1u : 0u;                                   \
                conf[t_] += g_ ? (x) : 0.0f;                                \
            }                                                               \
        }

    // ---- prologue: stage tile blockIdx.x into half 0 ----
    int tile = blockIdx.x;
    int2 clab = make_int2(0, 0);
    {
        float4 cur[5];
#pragma unroll
        for (int k = 0; k < 5; ++k) cur[k] = make_float4(0.f, 0.f, 0.f, 0.f);
        const int fb = tile * TF4;
#pragma unroll
        for (int k = 0; k < 5; ++k) {
            const int fi = fb + k * BLOCK + tid;
            if (fi < nf4) cur[k] = p4[fi];      // coalesced: 64 consecutive float4
        }
        const int pr0 = tile * TPAIRS + tid;
        if (pr0 < npairs) clab = l2[pr0];
#pragma unroll
        for (int k = 0; k < 5; ++k)
            *reinterpret_cast<float4*>(&s_lds[waddr[k]]) = cur[k];
    }
    __syncthreads();                            // covers staging + s_cor init

    int half = 0;
    while (tile < ntiles) {
        const int nt2 = tile + GRID;

        // ---- issue next tile's coalesced loads (land during compute) ----
        float4 nxt[5]; int2 nlab = make_int2(0, 0);
#pragma unroll
        for (int k = 0; k < 5; ++k) nxt[k] = make_float4(0.f, 0.f, 0.f, 0.f);
        if (nt2 < ntiles) {
            const int fb = nt2 * TF4;
#pragma unroll
            for (int k = 0; k < 5; ++k) {
                const int fi = fb + k * BLOCK + tid;
                if (fi < nf4) nxt[k] = p4[fi];
            }
            const int prn = nt2 * TPAIRS + tid;
            if (prn < npairs) nlab = l2[prn];
        }

        // ---- compute current tile from LDS ----
        const int pr = tile * TPAIRS + tid;
        if (pr < npairs) {
            const float* rb = &s_lds[half * HWORDS + tid * 20];
            const float4 c0 = *reinterpret_cast<const float4*>(rb + 0);
            const float4 c1 = *reinterpret_cast<const float4*>(rb + 4);
            const float4 c2 = *reinterpret_cast<const float4*>(rb + 8);
            const float4 c3 = *reinterpret_cast<const float4*>(rb + 12);
            const float4 c4 = *reinterpret_cast<const float4*>(rb + 16);
            ++np;

            conf[0] += (((c0.x + c0.y) + (c0.z + c0.w)) + ((c1.x + c1.y) + (c1.z + c1.w)))
                     + (((c2.x + c2.y) + (c2.z + c2.w)) + ((c3.x + c3.y) + (c3.z + c3.w)))
                     + ((c4.x + c4.y) + (c4.z + c4.w));

            LADDER_LOW(c0.x); LADDER_LOW(c0.y); LADDER_LOW(c0.z); LADDER_LOW(c0.w);
            LADDER_LOW(c1.x); LADDER_LOW(c1.y); LADDER_LOW(c1.z); LADDER_LOW(c1.w);
            LADDER_LOW(c2.x); LADDER_LOW(c2.y); LADDER_LOW(c2.z); LADDER_LOW(c2.w);
            LADDER_LOW(c3.x); LADDER_LOW(c3.y); LADDER_LOW(c3.z); LADDER_LOW(c3.w);
            LADDER_LOW(c4.x); LADDER_LOW(c4.y); LADDER_LOW(c4.z); LADDER_LOW(c4.w);

            const float mA = fmaxf(fmaxf(fmaxf(fmaxf(c0.x, c0.y), fmaxf(c0.z, c0.w)),
                                         fmaxf(fmaxf(c1.x, c1.y), fmaxf(c1.z, c1.w))),
                                   fmaxf(c2.x, c2.y));
            const float mB = fmaxf(fmaxf(fmaxf(fmaxf(c2.z, c2.w), fmaxf(c3.x, c3.y)),
                                         fmaxf(fmaxf(c3.z, c3.w), fmaxf(c4.x, c4.y))),
                                   fmaxf(c4.z, c4.w));
            LADDER_HIGH(mA);
            LADDER_HIGH(mB);

            float plA = c0.x;                   // p[label] via cndmask chain
            plA = (clab.x == 1) ? c0.y : plA;
            plA = (clab.x == 2) ? c0.z : plA;
            plA = (clab.x == 3) ? c0.w : plA;
            plA = (clab.x == 4) ? c1.x : plA;
            plA = (clab.x == 5) ? c1.y : plA;
            plA = (clab.x == 6) ? c1.z : plA;
            plA = (clab.x == 7) ? c1.w : plA;
            plA = (clab.x == 8) ? c2.x : plA;
            plA = (clab.x == 9) ? c2.y : plA;
            if (plA >= mA) {                    // max >= 0.1 -> bin idx >= 0
                const int im = min((int)ceilf(plA * 10.0f) - 1, NBINS - 1);
                atomicAdd(&s_cor[im], 1u);      // LDS only, ~10% hit rate
            }
            float plB = c2.z;
            plB = (clab.y == 1) ? c2.w : plB;
            plB = (clab.y == 2) ? c3.x : plB;
            plB = (clab.y == 3) ? c3.y : plB;
            plB = (clab.y == 4) ? c3.z : plB;
            plB = (clab.y == 5) ? c3.w : plB;
            plB = (clab.y == 6) ? c4.x : plB;
            plB = (clab.y == 7) ? c4.y : plB;
            plB = (clab.y == 8) ? c4.z : plB;
            plB = (clab.y == 9) ? c4.w : plB;
            if (plB >= mB) {
                const int im = min((int)ceilf(plB * 10.0f) - 1, NBINS - 1);
                atomicAdd(&s_cor[im], 1u);
            }
        }

        // ---- stage next tile into the other half ----
        {
            float* ob = &s_lds[(half ^ 1) * HWORDS];
#pragma unroll
            for (int k = 0; k < 5; ++k)
                *reinterpret_cast<float4*>(ob + waddr[k]) = nxt[k];
        }
        __syncthreads();                        // one barrier per tile
        half ^= 1; clab = nlab; tile = nt2;
    }
#undef LADDER_LOW
#undef LADDER_HIGH

    unsigned int cnt0 = 20u * np;               // all elements > 0 (softmax output)

    // ---- 64-lane butterfly ----
#pragma unroll
    for (int t = 0; t < NBINS; ++t)
        for (int o = 32; o > 0; o >>= 1)
            conf[t] += __shfl_xor(conf[t], o, 64);
    for (int o = 32; o > 0; o >>= 1) cnt0 += __shfl_xor(cnt0, o, 64);
#pragma unroll
    for (int t = 1; t < NBINS; ++t)
        for (int o = 32; o > 0; o >>= 1)
            cnt1[t] += __shfl_xor(cnt1[t], o, 64);

    if (lane == 0) {
#pragma unroll
        for (int t = 0; t < NBINS; ++t) {
            s_red[wave * NBINS + t]       = conf[t];
            s_red[(4 + wave) * NBINS + t] = (t == 0) ? (float)cnt0 : (float)cnt1[t];
        }
    }
    __syncthreads();

    if (tid < 12) {   // 12 slots (2 zero pads) so reduce can float4-load
        float fc = 0.0f, fn = 0.0f;
        if (tid < NBINS) {
#pragma unroll
            for (int w = 0; w < 4; ++w) {
                fc += s_red[w * NBINS + tid];
                fn += s_red[(4 + w) * NBINS + tid];
            }
        }
        const float fr = (tid < NBINS) ? (float)s_cor[tid] : 0.0f;
        part[(size_t)blockIdx.x * PSTR + tid]                   = fc;
        part[(size_t)GRID * PSTR + blockIdx.x * PSTR + tid]     = fn;
        part[(size_t)2 * GRID * PSTR + blockIdx.x * PSTR + tid] = fr;
    }
}

__global__ __launch_bounds__(256) void ece_reduce(
    const float* __restrict__ part,
    float* __restrict__ out)
{
    __shared__ double s_c[4][NBINS];
    __shared__ double s_n[4][NBINS];
    __shared__ double s_r[4][NBINS];

    const int tid = threadIdx.x;
    const int lane = tid & 63, wave = tid >> 6;

    double conf[NBINS], cntd[NBINS], cord[NBINS];
#pragma unroll
    for (int t = 0; t < NBINS; ++t) { conf[t] = 0.0; cntd[t] = 0.0; cord[t] = 0.0; }

    for (int b = tid; b < GRID; b += 256) {
        const float4* rc = reinterpret_cast<const float4*>(part + (size_t)b * PSTR);
        const float4* rn = reinterpret_cast<const float4*>(part + (size_t)GRID * PSTR + b * PSTR);
        const float4* rr = reinterpret_cast<const float4*>(part + (size_t)2 * GRID * PSTR + b * PSTR);
        const float4 c0 = rc[0], c1 = rc[1], c2 = rc[2];
        const float4 n0 = rn[0], n1 = rn[1], n2 = rn[2];
        const float4 r0 = rr[0], r1 = rr[1], r2 = rr[2];
        const float cf[12] = {c0.x,c0.y,c0.z,c0.w, c1.x,c1.y,c1.z,c1.w, c2.x,c2.y,c2.z,c2.w};
        const float nf[12] = {n0.x,n0.y,n0.z,n0.w, n1.x,n1.y,n1.z,n1.w, n2.x,n2.y,n2.z,n2.w};
        const float rf[12] = {r0.x,r0.y,r0.z,r0.w, r1.x,r1.y,r1.z,r1.w, r2.x,r2.y,r2.z,r2.w};
#pragma unroll
        for (int t = 0; t < NBINS; ++t) {
            conf[t] += (double)cf[t];
            cntd[t] += (double)nf[t];
            cord[t] += (double)rf[t];
        }
    }

#pragma unroll
    for (int t = 0; t < NBINS; ++t) {
        for (int o = 32; o > 0; o >>= 1) {
            conf[t] += __shfl_xor(conf[t], o, 64);
            cntd[t] += __shfl_xor(cntd[t], o, 64);
            cord[t] += __shfl_xor(cord[t], o, 64);
        }
    }
    if (lane == 0) {
#pragma unroll
        for (int t = 0; t < NBINS; ++t) {
            s_c[wave][t] = conf[t]; s_n[wave][t] = cntd[t]; s_r[wave][t] = cord[t];
        }
    }
    __syncthreads();

    if (tid == 0) {
        double S[NBINS + 1], G[NBINS + 1], R[NBINS];
        for (int t = 0; t < NBINS; ++t) {
            G[t] = s_n[0][t] + s_n[1][t] + s_n[2][t] + s_n[3][t];
            R[t] = s_r[0][t] + s_r[1][t] + s_r[2][t] + s_r[3][t];
            S[t] = s_c[0][t] + s_c[1][t] + s_c[2][t] + s_c[3][t];
        }
        S[NBINS] = 0.0; G[NBINS] = 0.0;

        double total = 0.0, ece = 0.0;
        for (int j = 0; j < NBINS; ++j) {
            const double c  = G[j] - G[j + 1];     // per-bin count
            const double sc = S[j] - S[j + 1];     // per-bin conf sum
            const double ba = R[j] / c;
            total += c;
            ece   += fabs(sc / c - ba) * c;
            out[1 + j]  = (float)((float)((j + 1) * 0.1) - 0.05f);  // centers
            out[11 + j] = (float)ba;
        }
        out[0] = (float)(ece / total);
    }
}

extern "C" void kernel_launch(void* const* d_in, const int* in_sizes, int n_in,
                              void* d_out, int out_size, void* d_ws, size_t ws_size,
                              hipStream_t stream)
{
    const float* probs  = (const float*)d_in[0];
    const int*   labels = (const int*)  d_in[1];
    float*       out    = (float*)d_out;
    const int n      = in_sizes[1];        // N_SAMPLES
    const int npairs = n / 2;
    const int nf4    = npairs * 5;         // float4 count
    const int ntiles = (npairs + TPAIRS - 1) / TPAIRS;

    float* part = (float*)d_ws;            // fully rewritten each call — no memset

    ece_pass<<<GRID, BLOCK, 0, stream>>>((const float4*)probs, (const int2*)labels,
                                         part, npairs, nf4, ntiles);
    ece_reduce<<<1, 256, 0, stream>>>(part, out);
}

// Round 14
// 36.210 us; speedup vs baseline: 1.2350x; 1.2350x over previous
//
#include <hip/hip_runtime.h>

#define NBINS 10

constexpr int BLOCK = 256;
constexpr int GRID  = 1024;
constexpr int PSTR  = 16;     // padded partial-row stride (floats, float4-aligned)

// d_ws float layout: 3 segments of GRID*PSTR floats:
//   seg0 conf cumulative S_t (t=1..9; slot0 written 0, S0 analytic = G0/10)
//   seg1 cnt  cumulative G_t (t=0..9)
//   seg2 cor  cumulative R_t (t=0..9)
// Every slot read by ece_reduce is rewritten every call — no memset needed.

__global__ __launch_bounds__(BLOCK) void ece_pass(
    const float4* __restrict__ p4,
    const int2*   __restrict__ l2,
    float*        __restrict__ part,
    int npairs)
{
    __shared__ float s_red[12 * NBINS];     // 4 waves x 3 arrays x 10

    const int tid  = threadIdx.x;
    const int lane = tid & 63, wave = tid >> 6;

    const float EDGE[NBINS] = {
        (float)(0*0.1), (float)(1*0.1), (float)(2*0.1), (float)(3*0.1), (float)(4*0.1),
        (float)(5*0.1), (float)(6*0.1), (float)(7*0.1), (float)(8*0.1), (float)(9*0.1)};

    float        conf[NBINS];   // [0] unused (analytic)
    unsigned int cnt1[NBINS];   // [0] unused (analytic)
    unsigned int cor[NBINS];    // cumulative correct counts
    unsigned int np = 0;
#pragma unroll
    for (int t = 0; t < NBINS; ++t) { conf[t] = 0.0f; cnt1[t] = 0u; cor[t] = 0u; }

    // low edges 0.1..0.4: every element can land here
#define LADDER_LOW(x)                                                       \
        {                                                                   \
            _Pragma("unroll")                                               \
            for (int t_ = 1; t_ <= 4; ++t_) {                               \
                const bool g_ = (x) > EDGE[t_];                             \
                cnt1[t_] += g_ ? 1u : 0u;                                   \
                conf[t_] += g_ ? (x) : 0.0f;                                \
            }                                                               \
        }
    // index-tracked argmax step (first-occurrence, matches jnp.argmax)
#define ASTEP(m, am, val, idx)                                              \
        { const bool b_ = (val) > (m); (m) = b_ ? (val) : (m);              \
          (am) = b_ ? (idx) : (am); }
    // per-sample finish: high edges on the max (sum==1 => only the max can
    // exceed 0.5) + cumulative correct counts sharing the same compares
#define FINISH(m, am, lbl)                                                  \
        {                                                                   \
            const bool corr_ = ((am) == (lbl));                             \
            cor[0] += corr_ ? 1u : 0u;                                      \
            _Pragma("unroll")                                               \
            for (int t_ = 1; t_ <= 4; ++t_) {                               \
                const bool g_ = (m) > EDGE[t_];                             \
                cor[t_] += (corr_ && g_) ? 1u : 0u;                         \
            }                                                               \
            _Pragma("unroll")                                               \
            for (int t_ = 5; t_ < NBINS; ++t_) {                            \
                const bool g_ = (m) > EDGE[t_];                             \
                cnt1[t_] += g_ ? 1u : 0u;                                   \
                conf[t_] += g_ ? (m) : 0.0f;                                \
                cor[t_]  += (corr_ && g_) ? 1u : 0u;                        \
            }                                                               \
        }

    // ---- software-pipelined main loop (R11 structure) ----
    const int stride = GRID * BLOCK;
    int pr = blockIdx.x * BLOCK + tid;

    float4 c0, c1, c2, c3, c4; int2 clab;
    if (pr < npairs) {
        const float4* rw = p4 + (size_t)pr * 5;
        c0 = rw[0]; c1 = rw[1]; c2 = rw[2]; c3 = rw[3]; c4 = rw[4];
        clab = l2[pr];
    }

    while (pr < npairs) {
        const int nx = pr + stride;
        float4 n0, n1, n2, n3, n4; int2 nlab;
        if (nx < npairs) {                      // issue next loads BEFORE compute
            const float4* rw = p4 + (size_t)nx * 5;
            n0 = rw[0]; n1 = rw[1]; n2 = rw[2]; n3 = rw[3]; n4 = rw[4];
            nlab = l2[nx];
        }

        ++np;

        // ---- low ladder over all 20 elements ----
        LADDER_LOW(c0.x); LADDER_LOW(c0.y); LADDER_LOW(c0.z); LADDER_LOW(c0.w);
        LADDER_LOW(c1.x); LADDER_LOW(c1.y); LADDER_LOW(c1.z); LADDER_LOW(c1.w);
        LADDER_LOW(c2.x); LADDER_LOW(c2.y); LADDER_LOW(c2.z); LADDER_LOW(c2.w);
        LADDER_LOW(c3.x); LADDER_LOW(c3.y); LADDER_LOW(c3.z); LADDER_LOW(c3.w);
        LADDER_LOW(c4.x); LADDER_LOW(c4.y); LADDER_LOW(c4.z); LADDER_LOW(c4.w);

        // ---- sample A: elems 0..9 ----
        {
            float m = c0.x; int am = 0;
            ASTEP(m, am, c0.y, 1); ASTEP(m, am, c0.z, 2); ASTEP(m, am, c0.w, 3);
            ASTEP(m, am, c1.x, 4); ASTEP(m, am, c1.y, 5); ASTEP(m, am, c1.z, 6);
            ASTEP(m, am, c1.w, 7); ASTEP(m, am, c2.x, 8); ASTEP(m, am, c2.y, 9);
            FINISH(m, am, clab.x);
        }
        // ---- sample B: elems 10..19 ----
        {
            float m = c2.z; int am = 0;
            ASTEP(m, am, c2.w, 1); ASTEP(m, am, c3.x, 2); ASTEP(m, am, c3.y, 3);
            ASTEP(m, am, c3.z, 4); ASTEP(m, am, c3.w, 5); ASTEP(m, am, c4.x, 6);
            ASTEP(m, am, c4.y, 7); ASTEP(m, am, c4.z, 8); ASTEP(m, am, c4.w, 9);
            FINISH(m, am, clab.y);
        }

        // ---- rotate pipeline ----
        pr = nx;
        c0 = n0; c1 = n1; c2 = n2; c3 = n3; c4 = n4; clab = nlab;
    }
#undef LADDER_LOW
#undef ASTEP
#undef FINISH

    unsigned int cnt0 = 20u * np;       // every element > 0 (softmax output)

    // ---- 64-lane butterflies ----
#pragma unroll
    for (int t = 1; t < NBINS; ++t)
        for (int o = 32; o > 0; o >>= 1)
            conf[t] += __shfl_xor(conf[t], o, 64);
    for (int o = 32; o > 0; o >>= 1) cnt0 += __shfl_xor(cnt0, o, 64);
#pragma unroll
    for (int t = 1; t < NBINS; ++t)
        for (int o = 32; o > 0; o >>= 1)
            cnt1[t] += __shfl_xor(cnt1[t], o, 64);
#pragma unroll
    for (int t = 0; t < NBINS; ++t)
        for (int o = 32; o > 0; o >>= 1)
            cor[t] += __shfl_xor(cor[t], o, 64);

    if (lane == 0) {
#pragma unroll
        for (int t = 0; t < NBINS; ++t) {
            s_red[wave * NBINS + t]            = (t == 0) ? 0.0f : conf[t];
            s_red[(4 + wave) * NBINS + t]      = (t == 0) ? (float)cnt0 : (float)cnt1[t];
            s_red[(8 + wave) * NBINS + t]      = (float)cor[t];
        }
    }
    __syncthreads();

    if (tid < 12) {   // 12 slots (2 zero pads) so reduce can float4-load
        float fc = 0.0f, fn = 0.0f, fr = 0.0f;
        if (tid < NBINS) {
#pragma unroll
            for (int w = 0; w < 4; ++w) {
                fc += s_red[w * NBINS + tid];
                fn += s_red[(4 + w) * NBINS + tid];
                fr += s_red[(8 + w) * NBINS + tid];
            }
        }
        part[(size_t)blockIdx.x * PSTR + tid]                   = fc;
        part[(size_t)GRID * PSTR + blockIdx.x * PSTR + tid]     = fn;
        part[(size_t)2 * GRID * PSTR + blockIdx.x * PSTR + tid] = fr;
    }
}

__global__ __launch_bounds__(256) void ece_reduce(
    const float* __restrict__ part,
    float* __restrict__ out)
{
    __shared__ double s_c[4][NBINS];
    __shared__ double s_n[4][NBINS];
    __shared__ double s_r[4][NBINS];

    const int tid = threadIdx.x;
    const int lane = tid & 63, wave = tid >> 6;

    double conf[NBINS], cntd[NBINS], cord[NBINS];
#pragma unroll
    for (int t = 0; t < NBINS; ++t) { conf[t] = 0.0; cntd[t] = 0.0; cord[t] = 0.0; }

    for (int b = tid; b < GRID; b += 256) {
        const float4* rc = reinterpret_cast<const float4*>(part + (size_t)b * PSTR);
        const float4* rn = reinterpret_cast<const float4*>(part + (size_t)GRID * PSTR + b * PSTR);
        const float4* rr = reinterpret_cast<const float4*>(part + (size_t)2 * GRID * PSTR + b * PSTR);
        const float4 c0 = rc[0], c1 = rc[1], c2 = rc[2];
        const float4 n0 = rn[0], n1 = rn[1], n2 = rn[2];
        const float4 r0 = rr[0], r1 = rr[1], r2 = rr[2];
        const float cf[12] = {c0.x,c0.y,c0.z,c0.w, c1.x,c1.y,c1.z,c1.w, c2.x,c2.y,c2.z,c2.w};
        const float nf[12] = {n0.x,n0.y,n0.z,n0.w, n1.x,n1.y,n1.z,n1.w, n2.x,n2.y,n2.z,n2.w};
        const float rf[12] = {r0.x,r0.y,r0.z,r0.w, r1.x,r1.y,r1.z,r1.w, r2.x,r2.y,r2.z,r2.w};
#pragma unroll
        for (int t = 0; t < NBINS; ++t) {
            conf[t] += (double)cf[t];
            cntd[t] += (double)nf[t];
            cord[t] += (double)rf[t];
        }
    }

#pragma unroll
    for (int t = 0; t < NBINS; ++t) {
        for (int o = 32; o > 0; o >>= 1) {
            conf[t] += __shfl_xor(conf[t], o, 64);
            cntd[t] += __shfl_xor(cntd[t], o, 64);
            cord[t] += __shfl_xor(cord[t], o, 64);
        }
    }
    if (lane == 0) {
#pragma unroll
        for (int t = 0; t < NBINS; ++t) {
            s_c[wave][t] = conf[t]; s_n[wave][t] = cntd[t]; s_r[wave][t] = cord[t];
        }
    }
    __syncthreads();

    if (tid == 0) {
        double S[NBINS + 1], G[NBINS + 1], R[NBINS + 1];
        for (int t = 0; t < NBINS; ++t) {
            G[t] = s_n[0][t] + s_n[1][t] + s_n[2][t] + s_n[3][t];
            R[t] = s_r[0][t] + s_r[1][t] + s_r[2][t] + s_r[3][t];
            S[t] = s_c[0][t] + s_c[1][t] + s_c[2][t] + s_c[3][t];
        }
        S[0] = G[0] / 10.0;           // sum(probs)==1 per sample: S0 = 2*pairs = G0/10
        S[NBINS] = 0.0; G[NBINS] = 0.0; R[NBINS] = 0.0;

        double total = 0.0, ece = 0.0;
        for (int j = 0; j < NBINS; ++j) {
            const double c  = G[j] - G[j + 1];     // per-bin count
            const double sc = S[j] - S[j + 1];     // per-bin conf sum
            const double cr = R[j] - R[j + 1];     // per-bin correct count
            const double ba = cr / c;
            total += c;
            ece   += fabs(sc / c - ba) * c;
            out[1 + j]  = (float)((float)((j + 1) * 0.1) - 0.05f);  // centers
            out[11 + j] = (float)ba;
        }
        out[0] = (float)(ece / total);
    }
}

extern "C" void kernel_launch(void* const* d_in, const int* in_sizes, int n_in,
                              void* d_out, int out_size, void* d_ws, size_t ws_size,
                              hipStream_t stream)
{
    const float* probs  = (const float*)d_in[0];
    const int*   labels = (const int*)  d_in[1];
    float*       out    = (float*)d_out;
    const int n      = in_sizes[1];       // N_SAMPLES
    const int npairs = n / 2;

    float* part = (float*)d_ws;           // fully rewritten each call — no memset

    ece_pass<<<GRID, BLOCK, 0, stream>>>((const float4*)probs, (const int2*)labels,
                                         part, npairs);
    ece_reduce<<<1, 256, 0, stream>>>(part, out);
}